// Round 1
// baseline (1271.365 us; speedup 1.0000x reference)
//
#include <hip/hip_runtime.h>
#include <hip/hip_bf16.h>
#include <math.h>

typedef __bf16 bf16x8 __attribute__((ext_vector_type(8)));
typedef float floatx4 __attribute__((ext_vector_type(4)));

#define BSZ 8
#define SEQ 2048
#define DIM 512
#define BKEY 32
#define BQ 32

__device__ __forceinline__ unsigned short f2bf(float f) {
    unsigned int u = __float_as_uint(f);
    u += 0x7fffu + ((u >> 16) & 1u);   // RNE
    return (unsigned short)(u >> 16);
}

// LDS layouts (bf16 elements, 8-element-chunk XOR swizzle, no padding):
//  Ksh: element (row,col)  at row*512 + ((col>>3 ^ (row&7))<<3) + (col&7)
//  Vsh: element (d,key)    at d*32   + ((key>>3 ^ (d&3))<<3)   + (key&7)   [transposed V]
//  Psh: per-wave 16x32     at r*32   + ((c>>3  ^ (r&3))<<3)    + (c&7)

__global__ __launch_bounds__(128, 2)
void attn_fwd(const float* __restrict__ Q, const float* __restrict__ K,
              const float* __restrict__ V, float* __restrict__ O)
{
    __shared__ unsigned short Ksh[BKEY * DIM];
    __shared__ unsigned short Vsh[DIM * BKEY];
    __shared__ unsigned short Psh[2 * 16 * BKEY];

    const int tid  = threadIdx.x;
    const int lane = tid & 63;
    const int wv   = tid >> 6;        // wave 0/1
    const int ml   = lane & 15;
    const int quad = lane >> 4;

    const int bid   = blockIdx.x;
    const int b     = bid & 7;                      // batch == XCD swizzle
    const int qtile = (SEQ / BQ - 1) - (bid >> 3);  // longest extents dispatch first
    const int q0    = qtile * BQ;
    const int nkt   = qtile + 1;                    // causal K-tile extent

    const float* Qb = Q + (size_t)b * SEQ * DIM;
    const float* Kb = K + (size_t)b * SEQ * DIM;
    const float* Vb = V + (size_t)b * SEQ * DIM;
    float*       Ob = O + (size_t)b * SEQ * DIM;

    // ---- preload Q fragments, A-layout: A[m=lane&15][k=quad*8+j] ----
    bf16x8 qf[16];
    {
        const float* qp = Qb + (size_t)(q0 + wv * 16 + ml) * DIM + quad * 8;
        #pragma unroll
        for (int kc = 0; kc < 16; ++kc) {
            float4 x = *(const float4*)(qp + kc * 32);
            float4 y = *(const float4*)(qp + kc * 32 + 4);
            union { bf16x8 v; unsigned short s[8]; } u;
            u.s[0]=f2bf(x.x); u.s[1]=f2bf(x.y); u.s[2]=f2bf(x.z); u.s[3]=f2bf(x.w);
            u.s[4]=f2bf(y.x); u.s[5]=f2bf(y.y); u.s[6]=f2bf(y.z); u.s[7]=f2bf(y.w);
            qf[kc] = u.v;
        }
    }

    floatx4 acc[32];
    #pragma unroll
    for (int i = 0; i < 32; ++i) acc[i] = (floatx4){0.f, 0.f, 0.f, 0.f};
    float mrun[4] = {-INFINITY, -INFINITY, -INFINITY, -INFINITY};
    float lrun[4] = {0.f, 0.f, 0.f, 0.f};

    const float CS = 1.4426950408889634f * 0.04419417382415922f; // log2(e)/sqrt(512)

    for (int kt = 0; kt < nkt; ++kt) {
        const int k0 = kt * BKEY;

        // ---- stage K tile: coalesced fp32 loads, bf16 swizzled LDS ----
        {
            const int col   = tid * 4;     // 0..508
            const int chunk = col >> 3;
            const int halfo = col & 7;     // 0 or 4
            #pragma unroll 4
            for (int r = 0; r < BKEY; ++r) {
                float4 x = *(const float4*)(Kb + (size_t)(k0 + r) * DIM + col);
                ushort4 us;
                us.x=f2bf(x.x); us.y=f2bf(x.y); us.z=f2bf(x.z); us.w=f2bf(x.w);
                *(ushort4*)&Ksh[r * DIM + (((chunk ^ (r & 7)) << 3) | halfo)] = us;
            }
        }
        // ---- stage V tile transposed: Vsh[d][key] ----
        {
            const int key = tid & 31;
            const int dg  = tid >> 5;      // 0..3
            const int kc8 = key >> 3, k7 = key & 7;
            #pragma unroll 4
            for (int d0 = dg * 4; d0 < DIM; d0 += 16) {
                float4 x = *(const float4*)(Vb + (size_t)(k0 + key) * DIM + d0);
                Vsh[(d0+0)*BKEY + (((kc8 ^ ((d0+0)&3))<<3) | k7)] = f2bf(x.x);
                Vsh[(d0+1)*BKEY + (((kc8 ^ ((d0+1)&3))<<3) | k7)] = f2bf(x.y);
                Vsh[(d0+2)*BKEY + (((kc8 ^ ((d0+2)&3))<<3) | k7)] = f2bf(x.z);
                Vsh[(d0+3)*BKEY + (((kc8 ^ ((d0+3)&3))<<3) | k7)] = f2bf(x.w);
            }
        }
        __syncthreads();

        // ---- S = Q K^T : two 16x16 n-tiles over the 32 keys ----
        floatx4 s0 = (floatx4){0,0,0,0}, s1 = (floatx4){0,0,0,0};
        const int r0 = ml, r1 = 16 + ml;
        const int sw = ml & 7;
        #pragma unroll
        for (int kc = 0; kc < 16; ++kc) {
            const int ch = kc * 4 + quad;
            bf16x8 kf0 = *(bf16x8*)&Ksh[r0 * DIM + (((ch ^ sw) & 63) << 3)];
            bf16x8 kf1 = *(bf16x8*)&Ksh[r1 * DIM + (((ch ^ sw) & 63) << 3)];
            s0 = __builtin_amdgcn_mfma_f32_16x16x32_bf16(qf[kc], kf0, s0, 0, 0, 0);
            s1 = __builtin_amdgcn_mfma_f32_16x16x32_bf16(qf[kc], kf1, s1, 0, 0, 0);
        }

        // ---- online softmax (C-layout: row = quad*4+r, col = nt*16 + ml) ----
        float z[2][4], pr[2][4], al[4], rs[4];
        #pragma unroll
        for (int r = 0; r < 4; ++r) {
            const int qg  = q0 + wv * 16 + quad * 4 + r;
            const int kg0 = k0 + ml, kg1 = k0 + 16 + ml;
            z[0][r] = (kg0 > qg) ? -INFINITY : s0[r] * CS;
            z[1][r] = (kg1 > qg) ? -INFINITY : s1[r] * CS;
        }
        #pragma unroll
        for (int r = 0; r < 4; ++r) {
            float v = fmaxf(z[0][r], z[1][r]);
            v = fmaxf(v, __shfl_xor(v, 1, 64));
            v = fmaxf(v, __shfl_xor(v, 2, 64));
            v = fmaxf(v, __shfl_xor(v, 4, 64));
            v = fmaxf(v, __shfl_xor(v, 8, 64));
            const float nm = fmaxf(mrun[r], v);
            al[r]   = __builtin_amdgcn_exp2f(mrun[r] - nm);
            mrun[r] = nm;
        }
        #pragma unroll
        for (int r = 0; r < 4; ++r) {
            pr[0][r] = __builtin_amdgcn_exp2f(z[0][r] - mrun[r]);
            pr[1][r] = __builtin_amdgcn_exp2f(z[1][r] - mrun[r]);
            float t = pr[0][r] + pr[1][r];
            t += __shfl_xor(t, 1, 64);
            t += __shfl_xor(t, 2, 64);
            t += __shfl_xor(t, 4, 64);
            t += __shfl_xor(t, 8, 64);
            rs[r] = t;
        }
        #pragma unroll
        for (int r = 0; r < 4; ++r) lrun[r] = lrun[r] * al[r] + rs[r];

        if (al[0] < 1.f || al[1] < 1.f || al[2] < 1.f || al[3] < 1.f) {
            #pragma unroll
            for (int nt = 0; nt < 32; ++nt) {
                acc[nt][0] *= al[0]; acc[nt][1] *= al[1];
                acc[nt][2] *= al[2]; acc[nt][3] *= al[3];
            }
        }

        // ---- P: C-layout -> A-layout via per-wave LDS round trip ----
        unsigned short* Pw = &Psh[wv * (16 * BKEY)];
        #pragma unroll
        for (int nt = 0; nt < 2; ++nt) {
            #pragma unroll
            for (int r = 0; r < 4; ++r) {
                const int row = quad * 4 + r, col = nt * 16 + ml;
                Pw[row * BKEY + ((((col >> 3) ^ (row & 3)) << 3) | (col & 7))] = f2bf(pr[nt][r]);
            }
        }
        asm volatile("s_waitcnt lgkmcnt(0)" ::: "memory");
        bf16x8 pf = *(bf16x8*)&Pw[ml * BKEY + ((quad ^ (ml & 3)) << 3)];

        // ---- O += P V ----
        #pragma unroll 8
        for (int nt = 0; nt < 32; ++nt) {
            const int drow = nt * 16 + ml;
            bf16x8 vf = *(bf16x8*)&Vsh[drow * BKEY + (((quad ^ (drow & 3)) << 3))];
            acc[nt] = __builtin_amdgcn_mfma_f32_16x16x32_bf16(pf, vf, acc[nt], 0, 0, 0);
        }
        __syncthreads();
    }

    // ---- epilogue: O / l ----
    float inv[4];
    #pragma unroll
    for (int r = 0; r < 4; ++r) inv[r] = 1.f / lrun[r];
    #pragma unroll 4
    for (int nt = 0; nt < 32; ++nt) {
        #pragma unroll
        for (int r = 0; r < 4; ++r) {
            const int row = q0 + wv * 16 + quad * 4 + r;
            Ob[(size_t)row * DIM + nt * 16 + ml] = acc[nt][r] * inv[r];
        }
    }
}

extern "C" void kernel_launch(void* const* d_in, const int* in_sizes, int n_in,
                              void* d_out, int out_size, void* d_ws, size_t ws_size,
                              hipStream_t stream) {
    const float* Q = (const float*)d_in[0];
    const float* K = (const float*)d_in[1];
    const float* V = (const float*)d_in[2];
    float* Out = (float*)d_out;
    // 8 batches x 64 causal q-tiles of 32 rows; blockIdx%8==batch (XCD locality),
    // q-tiles in descending work order (longest-first dispatch).
    attn_fwd<<<dim3(BSZ * (SEQ / BQ)), dim3(128), 0, stream>>>(Q, K, V, Out);
}

// Round 2
// 728.209 us; speedup vs baseline: 1.7459x; 1.7459x over previous
//
#include <hip/hip_runtime.h>
#include <hip/hip_bf16.h>
#include <math.h>

typedef __bf16 bf16x8 __attribute__((ext_vector_type(8)));
typedef float floatx4 __attribute__((ext_vector_type(4)));
typedef unsigned short ushort8_t __attribute__((ext_vector_type(8)));

#define BSZ 8
#define SEQ 2048
#define DIM 512
#define BKEY 32
#define BQ 32

__device__ __forceinline__ unsigned short f2bf(float f) {
    unsigned int u = __float_as_uint(f);
    u += 0x7fffu + ((u >> 16) & 1u);   // RNE
    return (unsigned short)(u >> 16);
}

// ---------- pre-pass 1: K fp32 -> bf16, same layout [b][k][d] ----------
__global__ __launch_bounds__(256) void conv_k(const float* __restrict__ K,
                                              unsigned short* __restrict__ Kb) {
    size_t i = ((size_t)blockIdx.x * 256 + threadIdx.x) * 8;
    float4 a = *(const float4*)(K + i);
    float4 b = *(const float4*)(K + i + 4);
    ushort8_t u;
    u[0]=f2bf(a.x); u[1]=f2bf(a.y); u[2]=f2bf(a.z); u[3]=f2bf(a.w);
    u[4]=f2bf(b.x); u[5]=f2bf(b.y); u[6]=f2bf(b.z); u[7]=f2bf(b.w);
    *(ushort8_t*)(Kb + i) = u;
}

// ---------- pre-pass 2: V fp32 [b][k][d] -> bf16 transposed [b][d][k] ----------
__global__ __launch_bounds__(256) void trans_v(const float* __restrict__ V,
                                               unsigned short* __restrict__ Vt) {
    __shared__ unsigned short T[64][65];
    const int tx = threadIdx.x & 63, ty = threadIdx.x >> 6;
    const int k0 = blockIdx.x * 64, d0 = blockIdx.y * 64, b = blockIdx.z;
    const float* Vb = V + (size_t)b * SEQ * DIM;
    unsigned short* Vtb = Vt + (size_t)b * DIM * SEQ;
    #pragma unroll
    for (int p = 0; p < 16; ++p) {
        const int r = p * 4 + ty;
        T[r][tx] = f2bf(Vb[(size_t)(k0 + r) * DIM + d0 + tx]);
    }
    __syncthreads();
    #pragma unroll
    for (int p = 0; p < 16; ++p) {
        const int r = p * 4 + ty;
        Vtb[(size_t)(d0 + r) * SEQ + k0 + tx] = T[tx][r];
    }
}

// LDS layouts (bf16 elements, 8-element-chunk XOR swizzle):
//  Ksh: (row,col) at row*512 + ((col>>3 ^ (row&7))<<3) + (col&7)
//  Vsh: (d,key)   at d*32   + ((key>>3 ^ (d&3))<<3)   + (key&7)
//  Psh: per-wave 16x32 at r*32 + ((c>>3 ^ (r&3))<<3) + (c&7)

template <bool WS>
__global__ __launch_bounds__(128, 2)
void attn_fwd(const float* __restrict__ Q, const float* __restrict__ K,
              const float* __restrict__ V, const unsigned short* __restrict__ Kb,
              const unsigned short* __restrict__ Vt, float* __restrict__ O)
{
    __shared__ unsigned short Ksh[BKEY * DIM];
    __shared__ unsigned short Vsh[DIM * BKEY];
    __shared__ unsigned short Psh[2 * 16 * BKEY];

    const int tid  = threadIdx.x;
    const int lane = tid & 63;
    const int wv   = tid >> 6;
    const int ml   = lane & 15;
    const int quad = lane >> 4;

    const int bid = blockIdx.x;
    const int b   = bid & 7;                 // batch == XCD swizzle (bid%8)
    const int idx = (bid & 255) >> 3;        // 0..31
    // complementary pairing: blocks bid and bid+256 land on the same CU
    // (round-robin heuristic) with qtiles summing to 63 -> ~65 K-tiles/CU.
    const int qtile = (bid < 256) ? (63 - idx) : idx;
    const int q0  = qtile * BQ;
    const int nkt = qtile + 1;

    const float* Qb = Q + (size_t)b * SEQ * DIM;
    const float* Kf = K + (size_t)b * SEQ * DIM;
    const float* Vf = V + (size_t)b * SEQ * DIM;
    const unsigned short* Kbb = Kb + (size_t)b * SEQ * DIM;
    const unsigned short* Vtb = Vt + (size_t)b * DIM * SEQ;
    float* Ob = O + (size_t)b * SEQ * DIM;

    // ---- preload Q fragments, A-layout: A[m=lane&15][k=quad*8+j] ----
    bf16x8 qf[16];
    {
        const float* qp = Qb + (size_t)(q0 + wv * 16 + ml) * DIM + quad * 8;
        #pragma unroll
        for (int kc = 0; kc < 16; ++kc) {
            float4 x = *(const float4*)(qp + kc * 32);
            float4 y = *(const float4*)(qp + kc * 32 + 4);
            union { bf16x8 v; unsigned short s[8]; } u;
            u.s[0]=f2bf(x.x); u.s[1]=f2bf(x.y); u.s[2]=f2bf(x.z); u.s[3]=f2bf(x.w);
            u.s[4]=f2bf(y.x); u.s[5]=f2bf(y.y); u.s[6]=f2bf(y.z); u.s[7]=f2bf(y.w);
            qf[kc] = u.v;
        }
    }

    floatx4 acc[32];
    #pragma unroll
    for (int i = 0; i < 32; ++i) acc[i] = (floatx4){0.f, 0.f, 0.f, 0.f};
    float mrun[4] = {-INFINITY, -INFINITY, -INFINITY, -INFINITY};
    float lrun[4] = {0.f, 0.f, 0.f, 0.f};

    const float CS = 1.4426950408889634f * 0.04419417382415922f; // log2(e)/sqrt(512)

    for (int kt = 0; kt < nkt; ++kt) {
        const int k0 = kt * BKEY;

        if constexpr (WS) {
            // ---- stage K tile from bf16 ws: 16 x ushort8 per thread ----
            #pragma unroll 4
            for (int i = 0; i < 16; ++i) {
                const int cid = i * 128 + tid;          // 0..2047
                const int row = cid >> 6, cc = cid & 63;
                ushort8_t v = *(const ushort8_t*)(Kbb + (size_t)(k0 + row) * DIM + cc * 8);
                *(ushort8_t*)&Ksh[row * DIM + ((cc ^ (row & 7)) << 3)] = v;
            }
            // ---- stage V tile from transposed bf16 ws ----
            #pragma unroll 4
            for (int i = 0; i < 16; ++i) {
                const int cid = i * 128 + tid;          // 0..2047
                const int d = cid >> 2, c = cid & 3;
                ushort8_t v = *(const ushort8_t*)(Vtb + (size_t)d * SEQ + k0 + c * 8);
                *(ushort8_t*)&Vsh[d * BKEY + ((c ^ (d & 3)) << 3)] = v;
            }
        } else {
            // ---- fallback: stage from fp32 with in-flight conversion ----
            {
                const int col   = tid * 4;
                const int chunk = col >> 3;
                const int halfo = col & 7;
                #pragma unroll 4
                for (int r = 0; r < BKEY; ++r) {
                    float4 x = *(const float4*)(Kf + (size_t)(k0 + r) * DIM + col);
                    ushort4 us;
                    us.x=f2bf(x.x); us.y=f2bf(x.y); us.z=f2bf(x.z); us.w=f2bf(x.w);
                    *(ushort4*)&Ksh[r * DIM + (((chunk ^ (r & 7)) << 3) | halfo)] = us;
                }
            }
            {
                const int key = tid & 31;
                const int dg  = tid >> 5;
                const int kc8 = key >> 3, k7 = key & 7;
                #pragma unroll 4
                for (int d0 = dg * 4; d0 < DIM; d0 += 16) {
                    float4 x = *(const float4*)(Vf + (size_t)(k0 + key) * DIM + d0);
                    Vsh[(d0+0)*BKEY + (((kc8 ^ ((d0+0)&3))<<3) | k7)] = f2bf(x.x);
                    Vsh[(d0+1)*BKEY + (((kc8 ^ ((d0+1)&3))<<3) | k7)] = f2bf(x.y);
                    Vsh[(d0+2)*BKEY + (((kc8 ^ ((d0+2)&3))<<3) | k7)] = f2bf(x.z);
                    Vsh[(d0+3)*BKEY + (((kc8 ^ ((d0+3)&3))<<3) | k7)] = f2bf(x.w);
                }
            }
        }
        __syncthreads();

        // ---- S = Q K^T ----
        floatx4 s0 = (floatx4){0,0,0,0}, s1 = (floatx4){0,0,0,0};
        const int r0 = ml, r1 = 16 + ml;
        const int sw = ml & 7;
        #pragma unroll
        for (int kc = 0; kc < 16; ++kc) {
            const int ch = kc * 4 + quad;
            bf16x8 kf0 = *(bf16x8*)&Ksh[r0 * DIM + ((ch ^ sw) << 3)];
            bf16x8 kf1 = *(bf16x8*)&Ksh[r1 * DIM + ((ch ^ sw) << 3)];
            s0 = __builtin_amdgcn_mfma_f32_16x16x32_bf16(qf[kc], kf0, s0, 0, 0, 0);
            s1 = __builtin_amdgcn_mfma_f32_16x16x32_bf16(qf[kc], kf1, s1, 0, 0, 0);
        }

        // ---- online softmax (C-layout: row = quad*4+r, col = nt*16+ml) ----
        float z[2][4], pr[2][4], al[4], rs[4];
        #pragma unroll
        for (int r = 0; r < 4; ++r) {
            const int qg  = q0 + wv * 16 + quad * 4 + r;
            const int kg0 = k0 + ml, kg1 = k0 + 16 + ml;
            z[0][r] = (kg0 > qg) ? -INFINITY : s0[r] * CS;
            z[1][r] = (kg1 > qg) ? -INFINITY : s1[r] * CS;
        }
        #pragma unroll
        for (int r = 0; r < 4; ++r) {
            float v = fmaxf(z[0][r], z[1][r]);
            v = fmaxf(v, __shfl_xor(v, 1, 64));
            v = fmaxf(v, __shfl_xor(v, 2, 64));
            v = fmaxf(v, __shfl_xor(v, 4, 64));
            v = fmaxf(v, __shfl_xor(v, 8, 64));
            const float nm = fmaxf(mrun[r], v);
            al[r]   = __builtin_amdgcn_exp2f(mrun[r] - nm);
            mrun[r] = nm;
        }
        #pragma unroll
        for (int r = 0; r < 4; ++r) {
            pr[0][r] = __builtin_amdgcn_exp2f(z[0][r] - mrun[r]);
            pr[1][r] = __builtin_amdgcn_exp2f(z[1][r] - mrun[r]);
            float t = pr[0][r] + pr[1][r];
            t += __shfl_xor(t, 1, 64);
            t += __shfl_xor(t, 2, 64);
            t += __shfl_xor(t, 4, 64);
            t += __shfl_xor(t, 8, 64);
            rs[r] = t;
        }
        #pragma unroll
        for (int r = 0; r < 4; ++r) lrun[r] = lrun[r] * al[r] + rs[r];

        if (al[0] < 1.f || al[1] < 1.f || al[2] < 1.f || al[3] < 1.f) {
            #pragma unroll
            for (int nt = 0; nt < 32; ++nt) {
                acc[nt][0] *= al[0]; acc[nt][1] *= al[1];
                acc[nt][2] *= al[2]; acc[nt][3] *= al[3];
            }
        }

        // ---- P: C-layout -> A-layout via per-wave LDS round trip ----
        unsigned short* Pw = &Psh[wv * (16 * BKEY)];
        #pragma unroll
        for (int nt = 0; nt < 2; ++nt) {
            #pragma unroll
            for (int r = 0; r < 4; ++r) {
                const int row = quad * 4 + r, col = nt * 16 + ml;
                Pw[row * BKEY + ((((col >> 3) ^ (row & 3)) << 3) | (col & 7))] = f2bf(pr[nt][r]);
            }
        }
        asm volatile("s_waitcnt lgkmcnt(0)" ::: "memory");
        bf16x8 pf = *(bf16x8*)&Pw[ml * BKEY + ((quad ^ (ml & 3)) << 3)];

        // ---- O += P V  (FULL unroll: acc must stay in registers) ----
        #pragma unroll
        for (int nt = 0; nt < 32; ++nt) {
            const int drow = nt * 16 + ml;
            bf16x8 vf = *(bf16x8*)&Vsh[drow * BKEY + ((quad ^ (drow & 3)) << 3)];
            acc[nt] = __builtin_amdgcn_mfma_f32_16x16x32_bf16(pf, vf, acc[nt], 0, 0, 0);
        }
        __syncthreads();
    }

    // ---- epilogue: O / l (FULL unroll) ----
    float inv[4];
    #pragma unroll
    for (int r = 0; r < 4; ++r) inv[r] = 1.f / lrun[r];
    #pragma unroll
    for (int nt = 0; nt < 32; ++nt) {
        #pragma unroll
        for (int r = 0; r < 4; ++r) {
            const int row = q0 + wv * 16 + quad * 4 + r;
            Ob[(size_t)row * DIM + nt * 16 + ml] = acc[nt][r] * inv[r];
        }
    }
}

extern "C" void kernel_launch(void* const* d_in, const int* in_sizes, int n_in,
                              void* d_out, int out_size, void* d_ws, size_t ws_size,
                              hipStream_t stream) {
    const float* Q = (const float*)d_in[0];
    const float* K = (const float*)d_in[1];
    const float* V = (const float*)d_in[2];
    float* Out = (float*)d_out;

    const size_t elems = (size_t)BSZ * SEQ * DIM;           // 8.39M
    const size_t need  = 2 * elems * sizeof(unsigned short); // 33.55 MB
    unsigned short* Kb = (unsigned short*)d_ws;
    unsigned short* Vt = Kb + elems;

    if (ws_size >= need) {
        conv_k<<<dim3(elems / 8 / 256), dim3(256), 0, stream>>>(K, Kb);
        trans_v<<<dim3(SEQ / 64, DIM / 64, BSZ), dim3(256), 0, stream>>>(V, Vt);
        attn_fwd<true><<<dim3(BSZ * (SEQ / BQ)), dim3(128), 0, stream>>>(Q, K, V, Kb, Vt, Out);
    } else {
        attn_fwd<false><<<dim3(BSZ * (SEQ / BQ)), dim3(128), 0, stream>>>(Q, K, V, Kb, Vt, Out);
    }
}

// Round 3
// 355.557 us; speedup vs baseline: 3.5757x; 2.0481x over previous
//
#include <hip/hip_runtime.h>
#include <math.h>

typedef __bf16 bf16x8 __attribute__((ext_vector_type(8)));
typedef float floatx4 __attribute__((ext_vector_type(4)));
typedef unsigned short ushort8_t __attribute__((ext_vector_type(8)));

#define BSZ 8
#define SEQ 2048
#define DIM 512
#define BKEY 32
#define BQ 32

__device__ __forceinline__ unsigned short f2bf(float f) {
    unsigned int u = __float_as_uint(f);
    u += 0x7fffu + ((u >> 16) & 1u);   // RNE
    return (unsigned short)(u >> 16);
}
__device__ __forceinline__ float bf2f(unsigned short s) {
    return __uint_as_float(((unsigned int)s) << 16);
}

// async global->LDS, 16B per lane. LDS dest is wave-uniform base + lane*16,
// so LDS layout is linear in chunk index; the bank swizzle is applied by
// permuting the *global* source address within its 1KB segment.
#define ASYNC16(g, l) __builtin_amdgcn_global_load_lds( \
    (const __attribute__((address_space(1))) unsigned int*)(g), \
    (__attribute__((address_space(3))) unsigned int*)(l), 16, 0, 0)

// ---------- pre-pass 1: K fp32 -> bf16 row-major [b][k][d] ----------
__global__ __launch_bounds__(256) void conv_k(const float* __restrict__ K,
                                              unsigned short* __restrict__ Kb) {
    size_t i = ((size_t)blockIdx.x * 256 + threadIdx.x) * 8;
    float4 a = *(const float4*)(K + i);
    float4 b = *(const float4*)(K + i + 4);
    ushort8_t u;
    u[0]=f2bf(a.x); u[1]=f2bf(a.y); u[2]=f2bf(a.z); u[3]=f2bf(a.w);
    u[4]=f2bf(b.x); u[5]=f2bf(b.y); u[6]=f2bf(b.z); u[7]=f2bf(b.w);
    *(ushort8_t*)(Kb + i) = u;
}

// ---------- pre-pass 2: V fp32 [b][k][d] -> bf16 tiled-transposed ----------
// Vt[(b*64 + ktile)*512*32 + d*32 + key] : each 32-key tile contiguous (32KB)
__global__ __launch_bounds__(256) void trans_v(const float* __restrict__ V,
                                               unsigned short* __restrict__ Vt) {
    __shared__ unsigned short T[BKEY][DIM + 8];
    const int bid = blockIdx.x;            // 8*64
    const int b = bid & 7, kb = bid >> 3;
    const float* src = V + ((size_t)b * SEQ + (size_t)kb * BKEY) * DIM;
    const int tid = threadIdx.x;
    #pragma unroll
    for (int i = 0; i < 16; ++i) {
        const int idx = i * 256 + tid;     // float4 idx, 4096 total
        const int key = idx >> 7;
        const int d = (idx & 127) * 4;
        float4 x = *(const float4*)(src + (size_t)key * DIM + d);
        T[key][d]   = f2bf(x.x);
        T[key][d+1] = f2bf(x.y);
        T[key][d+2] = f2bf(x.z);
        T[key][d+3] = f2bf(x.w);
    }
    __syncthreads();
    unsigned short* dst = Vt + (size_t)(b * (SEQ / BKEY) + kb) * DIM * BKEY;
    #pragma unroll
    for (int i = 0; i < 8; ++i) {
        const int cidx = i * 256 + tid;    // 16B chunk 0..2047
        const int d = cidx >> 2;
        const int kc = cidx & 3;
        ushort8_t v;
        #pragma unroll
        for (int k2 = 0; k2 < 8; ++k2) v[k2] = T[kc * 8 + k2][d];
        *(ushort8_t*)(dst + cidx * 8) = v;
    }
}

// Work-item decode (per batch, 160 items, big chunks first):
//  j<64: t=63-(j>>2), c=j&3 | j<112: t=47-(j-64)/3 | j<144: t=31-((j-112)>>1) | else t=159-j
// chunk c covers k-tiles [16c, min(16c+16, t+1)); only items with t>=16 split.

template <int SPLIT>
__global__ __launch_bounds__(128, 2)
void attn_fwd(const float* __restrict__ Q,
              const unsigned short* __restrict__ Kb,
              const unsigned short* __restrict__ Vt,
              unsigned short* __restrict__ PartO,
              float* __restrict__ Pml,
              float* __restrict__ O)
{
    __shared__ unsigned short Ksh[BKEY * DIM];    // chunk i <-> (row=i>>6, cc=i&63), holds ch=cc^(row&7)
    __shared__ unsigned short Vsh[DIM * BKEY];    // chunk i <-> (d=i>>2, cc=i&3), holds kc=cc^(d&3)
    __shared__ unsigned short Psh[2 * 16 * BKEY];

    const int tid  = threadIdx.x;
    const int lane = tid & 63;
    const int wv   = tid >> 6;
    const int ml   = lane & 15;
    const int quad = lane >> 4;

    const int bid = blockIdx.x;
    const int b   = bid & 7;
    const int j   = bid >> 3;
    int t, c;
    if (SPLIT) {
        if (j < 64)       { t = 63 - (j >> 2); c = j & 3; }
        else if (j < 112) { int u = j - 64; int q3 = u / 3; t = 47 - q3; c = u - q3 * 3; }
        else if (j < 144) { int u = j - 112; t = 31 - (u >> 1); c = u & 1; }
        else              { t = 159 - j; c = 0; }
    } else { t = 63 - j; c = 0; }
    const int kt0 = c * 16;
    const int kt1 = min(kt0 + 16, t + 1);
    const bool is_split = SPLIT && (t >= 16);
    const int q0 = t * BQ;

    const float* Qb = Q + (size_t)b * SEQ * DIM;
    const unsigned short* Kbb = Kb + (size_t)b * SEQ * DIM;
    const unsigned short* Vtb = Vt + (size_t)b * SEQ * DIM;   // tiled
    float* Ob = O + (size_t)b * SEQ * DIM;

    // ---- Q fragments, A-layout: A[m=lane&15][k=quad*8+j] ----
    bf16x8 qf[16];
    {
        const float* qp = Qb + (size_t)(q0 + wv * 16 + ml) * DIM + quad * 8;
        #pragma unroll
        for (int kc = 0; kc < 16; ++kc) {
            float4 x = *(const float4*)(qp + kc * 32);
            float4 y = *(const float4*)(qp + kc * 32 + 4);
            union { bf16x8 v; unsigned short s[8]; } u;
            u.s[0]=f2bf(x.x); u.s[1]=f2bf(x.y); u.s[2]=f2bf(x.z); u.s[3]=f2bf(x.w);
            u.s[4]=f2bf(y.x); u.s[5]=f2bf(y.y); u.s[6]=f2bf(y.z); u.s[7]=f2bf(y.w);
            qf[kc] = u.v;
        }
    }

    floatx4 acc[32];
    #pragma unroll
    for (int i = 0; i < 32; ++i) acc[i] = (floatx4){0.f, 0.f, 0.f, 0.f};
    float mrun[4] = {-INFINITY, -INFINITY, -INFINITY, -INFINITY};
    float lrun[4] = {0.f, 0.f, 0.f, 0.f};

    const float CS = 1.4426950408889634f * 0.04419417382415922f; // log2(e)/sqrt(512)

    for (int kt = kt0; kt < kt1; ++kt) {
        const int k0 = kt * BKEY;

        __syncthreads();   // prior iteration's LDS reads complete

        // ---- async stage K: 16 instr/thread, 1KB/wave-instr, swizzled source ----
        const unsigned short* Kt = Kbb + (size_t)k0 * DIM;
        #pragma unroll
        for (int i = 0; i < 16; ++i) {
            const int ci  = i * 128 + tid;
            const int row = ci >> 6;
            const int ch  = (ci & 63) ^ (row & 7);
            ASYNC16(Kt + (size_t)row * DIM + ch * 8, &Ksh[ci * 8]);
        }
        // ---- async stage V from contiguous tile ----
        const unsigned short* Vtile = Vtb + (size_t)kt * (DIM * BKEY);
        #pragma unroll
        for (int i = 0; i < 16; ++i) {
            const int ci = i * 128 + tid;
            const int d  = ci >> 2;
            const int kc = (ci & 3) ^ (d & 3);
            ASYNC16(Vtile + d * BKEY + kc * 8, &Vsh[ci * 8]);
        }
        __syncthreads();   // implies s_waitcnt vmcnt(0): staged data visible

        // ---- S = Q K^T : 4 accumulator chains for MFMA ILP ----
        floatx4 s0 = (floatx4){0,0,0,0}, s1 = (floatx4){0,0,0,0};
        floatx4 s0b = (floatx4){0,0,0,0}, s1b = (floatx4){0,0,0,0};
        const int sw = ml & 7;
        #pragma unroll
        for (int kc = 0; kc < 16; kc += 2) {
            const int ch0 = kc * 4 + quad, ch1 = (kc + 1) * 4 + quad;
            bf16x8 a0 = *(bf16x8*)&Ksh[ml * DIM + ((ch0 ^ sw) << 3)];
            bf16x8 a1 = *(bf16x8*)&Ksh[(16 + ml) * DIM + ((ch0 ^ sw) << 3)];
            bf16x8 b0 = *(bf16x8*)&Ksh[ml * DIM + ((ch1 ^ sw) << 3)];
            bf16x8 b1 = *(bf16x8*)&Ksh[(16 + ml) * DIM + ((ch1 ^ sw) << 3)];
            s0  = __builtin_amdgcn_mfma_f32_16x16x32_bf16(qf[kc],     a0, s0,  0, 0, 0);
            s1  = __builtin_amdgcn_mfma_f32_16x16x32_bf16(qf[kc],     a1, s1,  0, 0, 0);
            s0b = __builtin_amdgcn_mfma_f32_16x16x32_bf16(qf[kc + 1], b0, s0b, 0, 0, 0);
            s1b = __builtin_amdgcn_mfma_f32_16x16x32_bf16(qf[kc + 1], b1, s1b, 0, 0, 0);
        }
        s0 = s0 + s0b;
        s1 = s1 + s1b;

        // ---- online softmax (C-layout: row=quad*4+r, col=nt*16+ml) ----
        float z[2][4], pr[2][4], al[4], rs[4];
        if (kt == t) {  // diagonal tile: apply causal mask
            #pragma unroll
            for (int r = 0; r < 4; ++r) {
                const int qg = q0 + wv * 16 + quad * 4 + r;
                z[0][r] = (k0 + ml > qg)      ? -INFINITY : s0[r] * CS;
                z[1][r] = (k0 + 16 + ml > qg) ? -INFINITY : s1[r] * CS;
            }
        } else {
            #pragma unroll
            for (int r = 0; r < 4; ++r) { z[0][r] = s0[r] * CS; z[1][r] = s1[r] * CS; }
        }
        #pragma unroll
        for (int r = 0; r < 4; ++r) {
            float v = fmaxf(z[0][r], z[1][r]);
            v = fmaxf(v, __shfl_xor(v, 1, 64));
            v = fmaxf(v, __shfl_xor(v, 2, 64));
            v = fmaxf(v, __shfl_xor(v, 4, 64));
            v = fmaxf(v, __shfl_xor(v, 8, 64));
            const float nm = fmaxf(mrun[r], v);
            al[r]   = __builtin_amdgcn_exp2f(mrun[r] - nm);
            mrun[r] = nm;
        }
        #pragma unroll
        for (int r = 0; r < 4; ++r) {
            pr[0][r] = __builtin_amdgcn_exp2f(z[0][r] - mrun[r]);
            pr[1][r] = __builtin_amdgcn_exp2f(z[1][r] - mrun[r]);
            float s = pr[0][r] + pr[1][r];
            s += __shfl_xor(s, 1, 64);
            s += __shfl_xor(s, 2, 64);
            s += __shfl_xor(s, 4, 64);
            s += __shfl_xor(s, 8, 64);
            rs[r] = s;
        }
        #pragma unroll
        for (int r = 0; r < 4; ++r) lrun[r] = lrun[r] * al[r] + rs[r];

        if (al[0] < 1.f || al[1] < 1.f || al[2] < 1.f || al[3] < 1.f) {
            #pragma unroll
            for (int nt = 0; nt < 32; ++nt) {
                acc[nt][0] *= al[0]; acc[nt][1] *= al[1];
                acc[nt][2] *= al[2]; acc[nt][3] *= al[3];
            }
        }

        // ---- P: C-layout -> A-layout via per-wave LDS round trip ----
        unsigned short* Pw = &Psh[wv * (16 * BKEY)];
        #pragma unroll
        for (int nt = 0; nt < 2; ++nt) {
            #pragma unroll
            for (int r = 0; r < 4; ++r) {
                const int row = quad * 4 + r, col = nt * 16 + ml;
                Pw[row * BKEY + ((((col >> 3) ^ (row & 3)) << 3) | (col & 7))] = f2bf(pr[nt][r]);
            }
        }
        asm volatile("s_waitcnt lgkmcnt(0)" ::: "memory");
        bf16x8 pf = *(bf16x8*)&Pw[ml * BKEY + ((quad ^ (ml & 3)) << 3)];

        // ---- O += P V ----
        #pragma unroll
        for (int nt = 0; nt < 32; ++nt) {
            const int drow = nt * 16 + ml;
            bf16x8 vf = *(bf16x8*)&Vsh[drow * BKEY + ((quad ^ (drow & 3)) << 3)];
            acc[nt] = __builtin_amdgcn_mfma_f32_16x16x32_bf16(pf, vf, acc[nt], 0, 0, 0);
        }
    }

    if (!is_split) {
        float inv[4];
        #pragma unroll
        for (int r = 0; r < 4; ++r) inv[r] = 1.f / lrun[r];
        #pragma unroll
        for (int nt = 0; nt < 32; ++nt) {
            #pragma unroll
            for (int r = 0; r < 4; ++r) {
                const int row = q0 + wv * 16 + quad * 4 + r;
                Ob[(size_t)row * DIM + nt * 16 + ml] = acc[nt][r] * inv[r];
            }
        }
    } else {
        const size_t slot = (size_t)(b * 144 + j);
        unsigned short* po = PartO + slot * (BQ * DIM);
        #pragma unroll
        for (int nt = 0; nt < 32; ++nt) {
            #pragma unroll
            for (int r = 0; r < 4; ++r) {
                const int prow = wv * 16 + quad * 4 + r;
                po[prow * DIM + nt * 16 + ml] = f2bf(acc[nt][r]);
            }
        }
        if (ml == 0) {
            #pragma unroll
            for (int r = 0; r < 4; ++r) {
                const int prow = wv * 16 + quad * 4 + r;
                Pml[slot * 64 + prow * 2]     = mrun[r];
                Pml[slot * 64 + prow * 2 + 1] = lrun[r];
            }
        }
    }
}

// ---------- merge pass: combine 2..4 chunk partials per (b, t>=16) ----------
__global__ __launch_bounds__(256)
void attn_merge(const unsigned short* __restrict__ PartO,
                const float* __restrict__ Pml,
                float* __restrict__ O)
{
    const int bid = blockIdx.x;           // 8*48
    const int b = bid & 7;
    const int t = 16 + (bid >> 3);
    const int nc = (t >> 4) + 1;          // 2..4
    int j0;
    if (t >= 48)      j0 = (63 - t) * 4;
    else if (t >= 32) j0 = 64 + (47 - t) * 3;
    else              j0 = 112 + (31 - t) * 2;

    const int r  = threadIdx.x >> 3;       // row 0..31
    const int d0 = (threadIdx.x & 7) * 64; // 64 d-elements per thread

    float m[4], l[4];
    float M = -INFINITY;
    for (int cc = 0; cc < nc; ++cc) {
        const size_t slot = (size_t)(b * 144 + j0 + cc);
        m[cc] = Pml[slot * 64 + r * 2];
        l[cc] = Pml[slot * 64 + r * 2 + 1];
        M = fmaxf(M, m[cc]);
    }
    float L = 0.f;
    for (int cc = 0; cc < nc; ++cc) L += l[cc] * __builtin_amdgcn_exp2f(m[cc] - M);

    float o[64];
    #pragma unroll
    for (int i = 0; i < 64; ++i) o[i] = 0.f;
    for (int cc = 0; cc < nc; ++cc) {
        const size_t slot = (size_t)(b * 144 + j0 + cc);
        const float w = __builtin_amdgcn_exp2f(m[cc] - M);
        const unsigned short* po = PartO + slot * (BQ * DIM) + (size_t)r * DIM + d0;
        #pragma unroll
        for (int i = 0; i < 8; ++i) {
            ushort8_t v = *(const ushort8_t*)(po + i * 8);
            #pragma unroll
            for (int k2 = 0; k2 < 8; ++k2) o[i * 8 + k2] += w * bf2f(v[k2]);
        }
    }
    const float invL = 1.f / L;
    float* out = O + ((size_t)b * SEQ + (size_t)t * BQ + r) * DIM + d0;
    #pragma unroll
    for (int i = 0; i < 16; ++i) {
        float4 v4 = { o[i*4] * invL, o[i*4+1] * invL, o[i*4+2] * invL, o[i*4+3] * invL };
        *(float4*)(out + i * 4) = v4;
    }
}

extern "C" void kernel_launch(void* const* d_in, const int* in_sizes, int n_in,
                              void* d_out, int out_size, void* d_ws, size_t ws_size,
                              hipStream_t stream) {
    const float* Q = (const float*)d_in[0];
    const float* K = (const float*)d_in[1];
    const float* V = (const float*)d_in[2];
    float* Out = (float*)d_out;

    const size_t elems = (size_t)BSZ * SEQ * DIM;                 // 8.39M
    unsigned short* Kb = (unsigned short*)d_ws;
    unsigned short* Vt = Kb + elems;
    unsigned short* PartO = Vt + elems;
    float* Pml = (float*)(PartO + (size_t)BSZ * 144 * BQ * DIM);

    const size_t need_split = 2 * elems * 2                       // Kb + Vt
                            + (size_t)BSZ * 144 * BQ * DIM * 2    // PartO bf16
                            + (size_t)BSZ * 144 * 64 * 4;         // Pml
    conv_k<<<dim3(elems / 8 / 256), dim3(256), 0, stream>>>(K, Kb);
    trans_v<<<dim3(BSZ * (SEQ / BKEY)), dim3(256), 0, stream>>>(V, Vt);

    if (ws_size >= need_split) {
        attn_fwd<1><<<dim3(BSZ * 160), dim3(128), 0, stream>>>(Q, Kb, Vt, PartO, Pml, Out);
        attn_merge<<<dim3(BSZ * 48), dim3(256), 0, stream>>>(PartO, Pml, Out);
    } else {
        attn_fwd<0><<<dim3(BSZ * 64), dim3(128), 0, stream>>>(Q, Kb, Vt, PartO, Pml, Out);
    }
}